// Round 5
// baseline (557.668 us; speedup 1.0000x reference)
//
#include <hip/hip_runtime.h>
#include <hip/hip_bf16.h>
#include <math.h>

typedef __bf16 bf16x8 __attribute__((ext_vector_type(8)));
typedef __bf16 bf16x4 __attribute__((ext_vector_type(4)));
typedef unsigned short u16x8 __attribute__((ext_vector_type(8)));
typedef float  f32x4  __attribute__((ext_vector_type(4)));

constexpr int kS   = 2048;
constexpr int kH   = 4096;
constexpr int kNH  = 32;
constexpr int kNKV = 8;
constexpr int kHD  = 128;
constexpr int kQKV = kH + 2 * kNKV * kHD;   // 6144: [Q 4096 | K 1024 | V 1024]
constexpr int kKOff = kH;                    // 4096
constexpr int kVOff = kH + kNKV * kHD;       // 5120

// ---------------------------------------------------------------- generic cast
__global__ void cast_bf16(const float* __restrict__ in, __bf16* __restrict__ out, int n4) {
    int i = blockIdx.x * blockDim.x + threadIdx.x;
    if (i < n4) {
        float4 f = ((const float4*)in)[i];
        bf16x4 o;
        o[0] = (__bf16)f.x; o[1] = (__bf16)f.y; o[2] = (__bf16)f.z; o[3] = (__bf16)f.w;
        ((bf16x4*)out)[i] = o;
    }
}

// ---------------------------------------------------------------- fused cast: x -> xb, wq|wk|wv -> wqkv
__global__ void cast_all(const float* __restrict__ x, const float* __restrict__ wq,
                         const float* __restrict__ wk, const float* __restrict__ wv,
                         __bf16* __restrict__ xb, __bf16* __restrict__ wqkv) {
    int i = blockIdx.x * 256 + threadIdx.x;
    float4 f;
    __bf16* dst;
    int di;
    if (i < (1 << 21)) {
        f = ((const float4*)x)[i];
        dst = xb; di = i;
    } else {
        int j = i - (1 << 21);
        const float4* s = (j < (1 << 22)) ? ((const float4*)wq + j)
                        : (j < (5 << 20)) ? ((const float4*)wk + (j - (1 << 22)))
                                          : ((const float4*)wv + (j - (5 << 20)));
        f = *s;
        dst = wqkv; di = j;
    }
    bf16x4 o;
    o[0] = (__bf16)f.x; o[1] = (__bf16)f.y; o[2] = (__bf16)f.z; o[3] = (__bf16)f.w;
    ((bf16x4*)dst)[di] = o;
}

// ---------------------------------------------------------------- m97-style NT GEMM, BK=64, XOR-swizzled LDS
constexpr int BM = 128, BN = 128, BK = 64;

__device__ inline void gld16(const __bf16* g, __bf16* l) {
    __builtin_amdgcn_global_load_lds((const __attribute__((address_space(1))) void*)g,
                                     (__attribute__((address_space(3))) void*)l, 16, 0, 0);
}

template <typename OutT>
__global__ __launch_bounds__(256) void gemm_nt(const __bf16* __restrict__ A,
                                               const __bf16* __restrict__ B,
                                               OutT* __restrict__ C,
                                               int M, int N, int K) {
    __shared__ __align__(16) __bf16 As[BM * BK];   // 16 KB
    __shared__ __align__(16) __bf16 Bs[BN * BK];   // 16 KB
    const int tid  = threadIdx.x;
    const int w    = tid >> 6, lane = tid & 63;
    const int m0   = blockIdx.y * BM, n0 = blockIdx.x * BN;
    const int wm   = (w >> 1) * 64, wn = (w & 1) * 64;
    const int lr   = lane & 15, g8 = lane >> 4;

    const int l3 = lane >> 3;
    const int lc = (lane & 7) ^ l3;
    const __bf16 *gA[4], *gB[4];
    __bf16 *lA[4], *lB[4];
#pragma unroll
    for (int c = 0; c < 4; c++) {
        int G = w * 4 + c;
        gA[c] = A + (size_t)(m0 + G * 8 + l3) * K + lc * 8;
        gB[c] = B + (size_t)(n0 + G * 8 + l3) * K + lc * 8;
        lA[c] = As + G * 512;
        lB[c] = Bs + G * 512;
    }

    f32x4 acc[4][4];
#pragma unroll
    for (int i = 0; i < 4; i++)
#pragma unroll
        for (int j = 0; j < 4; j++) acc[i][j] = (f32x4)(0.f);

    for (int k0 = 0; k0 < K; k0 += BK) {
#pragma unroll
        for (int c = 0; c < 4; c++) {
            gld16(gA[c] + k0, lA[c]);
            gld16(gB[c] + k0, lB[c]);
        }
        __syncthreads();

        const int rx = lr & 7;
#pragma unroll
        for (int kc = 0; kc < 2; kc++) {
            bf16x8 af[4], bfr[4];
#pragma unroll
            for (int i = 0; i < 4; i++)
                af[i]  = *(const bf16x8*)&As[(wm + i * 16 + lr) * BK + (((kc * 4 + g8) ^ rx) * 8)];
#pragma unroll
            for (int j = 0; j < 4; j++)
                bfr[j] = *(const bf16x8*)&Bs[(wn + j * 16 + lr) * BK + (((kc * 4 + g8) ^ rx) * 8)];
#pragma unroll
            for (int i = 0; i < 4; i++)
#pragma unroll
                for (int j = 0; j < 4; j++)
                    acc[i][j] = __builtin_amdgcn_mfma_f32_16x16x32_bf16(af[i], bfr[j], acc[i][j], 0, 0, 0);
        }
        __syncthreads();
    }

    const int cr = g8 * 4, cc = lr;
#pragma unroll
    for (int i = 0; i < 4; i++)
#pragma unroll
        for (int j = 0; j < 4; j++) {
            OutT* Cp = C + (size_t)(m0 + wm + i * 16 + cr) * N + (n0 + wn + j * 16 + cc);
#pragma unroll
            for (int r = 0; r < 4; r++) Cp[(size_t)r * N] = (OutT)acc[i][j][r];
        }
}

// ---------------------------------------------------------------- RoPE in-place on qkv bf16 [S, 6144]
__global__ void rope_qkv(__bf16* __restrict__ qkv) {
    int idx  = blockIdx.x * 256 + threadIdx.x;   // S * 40 * 64
    int d    = idx & 63;
    int rest = idx >> 6;
    int hh   = rest % (kNH + kNKV);
    int s    = rest / (kNH + kNKV);
    float inv_freq = powf(500000.0f, -(float)d * (1.0f / 64.0f));
    float sn, cs;
    sincosf((float)s * inv_freq, &sn, &cs);
    __bf16* base = qkv + (size_t)s * kQKV + ((hh < kNH) ? hh * kHD : kKOff + (hh - kNH) * kHD);
    float sc = (hh < kNH) ? 0.088388347648318447f : 1.0f;
    float a = (float)base[d], b = (float)base[d + 64];
    base[d]      = (__bf16)((a * cs - b * sn) * sc);
    base[d + 64] = (__bf16)((b * cs + a * sn) * sc);
}

// ---------------------------------------------------------------- MFMA flash attention (GQA)
// block = (kvh, q-tile pair (pi, 127-pi)); wave w = q-head kvh*4+w.
// Ks: XOR-swizzled [64k][128d] via global_load_lds. Vt: transposed [128d][64k],
// conflict-free write mapping. Ps: bf16 P round-trip (C-layout -> A-layout).
constexpr int VTP = 72;    // Vt row stride elems
constexpr int PSB = 72;    // Ps row stride elems (bf16)

__global__ __launch_bounds__(256) void flash_attn(const __bf16* __restrict__ qkv,
                                                  __bf16* __restrict__ ob) {
    __shared__ __align__(16) __bf16 Ks[64 * 128];        // 16 KB, swizzled
    __shared__ __align__(16) __bf16 Vt[128 * VTP];       // 18 KB
    __shared__ __align__(16) __bf16 Ps[4 * 16 * PSB];    // 9 KB

    const int tid  = threadIdx.x;
    const int wave = tid >> 6, lane = tid & 63;
    const int bx   = blockIdx.x;
    const int kvh  = bx & 7;
    const int pi   = bx >> 3;                      // 0..63
    const int h    = kvh * 4 + wave;
    const int r    = lane & 15, g = lane >> 4;

    __bf16* Pw = Ps + wave * 16 * PSB;
    const __bf16* kbase = qkv + kKOff + kvh * kHD;
    const __bf16* vbase = qkv + kVOff + kvh * kHD;

    // K staging geometry (global_load_lds, slot = chunk ^ (row&15))
    int krow[4], kgc[4];
#pragma unroll
    for (int c = 0; c < 4; c++) {
        krow[c] = wave * 16 + c * 4 + (lane >> 4);
        kgc[c]  = (lane & 15) ^ (krow[c] & 15);
    }

    for (int qp = 0; qp < 2; qp++) {
        const int qt = qp ? pi : 127 - pi;
        const int qglob = qt * 16 + r;

        bf16x8 qfrag[4];
        const __bf16* qrow = qkv + (size_t)(qt * 16 + r) * kQKV + h * kHD + g * 8;
#pragma unroll
        for (int c = 0; c < 4; c++) qfrag[c] = *(const bf16x8*)(qrow + c * 32);

        f32x4 o[8];
#pragma unroll
        for (int dt = 0; dt < 8; dt++) o[dt] = (f32x4)(0.f);
        float mrow = -3.0e38f, lrow = 0.f;

        const int nkt = qt / 4 + 1;
        for (int kt = 0; kt < nkt; ++kt) {
            // ---- stage K via async global->LDS (swizzled)
#pragma unroll
            for (int c = 0; c < 4; c++)
                gld16(kbase + (size_t)(kt * 64 + krow[c]) * kQKV + kgc[c] * 8,
                      Ks + (wave * 4 + c) * 512);
            // ---- stage V transposed: conflict-free mapping (2-way max)
#pragma unroll
            for (int i = 0; i < 2; i++) {
                int task = i * 256 + tid;
                int p = task & 31, c = task >> 5;   // p: key pair, c: 8-d chunk
                const __bf16* v0 = vbase + (size_t)(kt * 64 + 2 * p) * kQKV + c * 8;
                u16x8 a = __builtin_bit_cast(u16x8, *(const bf16x8*)v0);
                u16x8 b = __builtin_bit_cast(u16x8, *(const bf16x8*)(v0 + kQKV));
#pragma unroll
                for (int j = 0; j < 8; j++) {
                    unsigned int pk = (unsigned int)a[j] | ((unsigned int)b[j] << 16);
                    *(unsigned int*)(Vt + (c * 8 + j) * VTP + 2 * p) = pk;
                }
            }
            __syncthreads();

            // ---- S^T = K·Q^T  (Ks read honors the XOR swizzle)
            f32x4 st[4];
#pragma unroll
            for (int t = 0; t < 4; t++) st[t] = (f32x4)(0.f);
#pragma unroll
            for (int c = 0; c < 4; c++) {
#pragma unroll
                for (int t = 0; t < 4; t++) {
                    bf16x8 kf = *(const bf16x8*)&Ks[(t * 16 + r) * 128 + (((c * 4 + g) ^ r) * 8)];
                    st[t] = __builtin_amdgcn_mfma_f32_16x16x32_bf16(kf, qfrag[c], st[t], 0, 0, 0);
                }
            }

            // ---- causal mask: only the diagonal tile can violate
            if (kt == nkt - 1) {
#pragma unroll
                for (int t = 0; t < 4; t++)
#pragma unroll
                    for (int reg = 0; reg < 4; reg++) {
                        int key = kt * 64 + t * 16 + g * 4 + reg;
                        if (key > qglob) st[t][reg] = -3.0e38f;
                    }
            }

            // ---- online softmax (per q = r)
            float mloc = -3.0e38f;
#pragma unroll
            for (int t = 0; t < 4; t++)
#pragma unroll
                for (int reg = 0; reg < 4; reg++) mloc = fmaxf(mloc, st[t][reg]);
            mloc = fmaxf(mloc, __shfl_xor(mloc, 16));
            mloc = fmaxf(mloc, __shfl_xor(mloc, 32));
            float mnew  = fmaxf(mrow, mloc);
            float alpha = __expf(mrow - mnew);
            mrow = mnew;
            float lsum = 0.f;
#pragma unroll
            for (int t = 0; t < 4; t++)
#pragma unroll
                for (int reg = 0; reg < 4; reg++) {
                    float pv = __expf(st[t][reg] - mnew);
                    st[t][reg] = pv;
                    lsum += pv;
                }
            lsum += __shfl_xor(lsum, 16);
            lsum += __shfl_xor(lsum, 32);
            lrow = lrow * alpha + lsum;

            float ar[4];
#pragma unroll
            for (int reg = 0; reg < 4; reg++) ar[reg] = __shfl(alpha, g * 4 + reg);
#pragma unroll
            for (int dt = 0; dt < 8; dt++)
#pragma unroll
                for (int reg = 0; reg < 4; reg++) o[dt][reg] *= ar[reg];

            // ---- P (bf16): C-layout -> LDS -> A-layout (wave-private)
#pragma unroll
            for (int t = 0; t < 4; t++) {
                bf16x4 pb;
#pragma unroll
                for (int j = 0; j < 4; j++) pb[j] = (__bf16)st[t][j];
                *(bf16x4*)&Pw[r * PSB + t * 16 + g * 4] = pb;
            }
            __asm__ volatile("s_waitcnt lgkmcnt(0)" ::: "memory");

#pragma unroll
            for (int kc = 0; kc < 2; kc++) {
                bf16x8 pf = *(const bf16x8*)&Pw[r * PSB + kc * 32 + g * 8];
#pragma unroll
                for (int dt = 0; dt < 8; dt++) {
                    bf16x8 vf = *(const bf16x8*)&Vt[(dt * 16 + r) * VTP + kc * 32 + g * 8];
                    o[dt] = __builtin_amdgcn_mfma_f32_16x16x32_bf16(pf, vf, o[dt], 0, 0, 0);
                }
            }
            __syncthreads();
        }

        // ---- epilogue
        float linv = 1.f / lrow;
        float lr4[4];
#pragma unroll
        for (int reg = 0; reg < 4; reg++) lr4[reg] = __shfl(linv, g * 4 + reg);
#pragma unroll
        for (int dt = 0; dt < 8; dt++)
#pragma unroll
            for (int reg = 0; reg < 4; reg++) {
                int qq = g * 4 + reg, dd = dt * 16 + r;
                ob[(size_t)(qt * 16 + qq) * kH + h * kHD + dd] = (__bf16)(o[dt][reg] * lr4[reg]);
            }
    }
}

// ---------------------------------------------------------------- launch
extern "C" void kernel_launch(void* const* d_in, const int* in_sizes, int n_in,
                              void* d_out, int out_size, void* d_ws, size_t ws_size,
                              hipStream_t stream) {
    const float* x  = (const float*)d_in[0];
    const float* wq = (const float*)d_in[1];
    const float* wk = (const float*)d_in[2];
    const float* wv = (const float*)d_in[3];
    const float* wo = (const float*)d_in[4];
    float* out = (float*)d_out;

    char* p = (char*)d_ws;
    auto alloc = [&](size_t bytes) {
        char* r = p;
        p += (bytes + 255) & ~(size_t)255;
        return r;
    };
    __bf16* xb    = (__bf16*)alloc((size_t)kS * kH * 2);        // 16 MB; later attn out
    __bf16* wqkvb = (__bf16*)alloc((size_t)kQKV * kH * 2);      // 48 MB; later wo bf16
    __bf16* qkv   = (__bf16*)alloc((size_t)kS * kQKV * 2);      // 24 MB
    __bf16* ao    = xb;
    __bf16* wob   = wqkvb;

    cast_all<<<dim3(1 << 15), 256, 0, stream>>>(x, wq, wk, wv, xb, wqkvb);

    gemm_nt<__bf16><<<dim3(kQKV / BN, kS / BM), 256, 0, stream>>>(xb, wqkvb, qkv, kS, kQKV, kH);

    rope_qkv<<<dim3(kS * (kNH + kNKV) * 64 / 256), 256, 0, stream>>>(qkv);

    cast_bf16<<<dim3((kH * kH / 4) / 256), 256, 0, stream>>>(wo, wob, kH * kH / 4);

    flash_attn<<<dim3(kNKV * 64), 256, 0, stream>>>(qkv, ao);

    gemm_nt<float><<<dim3(kH / BN, kS / BM), 256, 0, stream>>>(ao, wob, out, kS, kH, kH);
}

// Round 6
// 528.091 us; speedup vs baseline: 1.0560x; 1.0560x over previous
//
#include <hip/hip_runtime.h>
#include <hip/hip_bf16.h>
#include <math.h>

typedef __bf16 bf16x8 __attribute__((ext_vector_type(8)));
typedef __bf16 bf16x4 __attribute__((ext_vector_type(4)));
typedef unsigned short u16x8 __attribute__((ext_vector_type(8)));
typedef float  f32x4  __attribute__((ext_vector_type(4)));

constexpr int kS   = 2048;
constexpr int kH   = 4096;
constexpr int kNH  = 32;
constexpr int kNKV = 8;
constexpr int kHD  = 128;
constexpr int kQKV = kH + 2 * kNKV * kHD;   // 6144: [Q 4096 | K 1024 | V 1024]
constexpr int kKOff = kH;                    // 4096
constexpr int kVOff = kH + kNKV * kHD;       // 5120

// ---------------------------------------------------------------- generic cast
__global__ void cast_bf16(const float* __restrict__ in, __bf16* __restrict__ out, int n4) {
    int i = blockIdx.x * blockDim.x + threadIdx.x;
    if (i < n4) {
        float4 f = ((const float4*)in)[i];
        bf16x4 o;
        o[0] = (__bf16)f.x; o[1] = (__bf16)f.y; o[2] = (__bf16)f.z; o[3] = (__bf16)f.w;
        ((bf16x4*)out)[i] = o;
    }
}

// ---------------------------------------------------------------- fused cast: x -> xb, wq|wk|wv -> wqkv
__global__ void cast_all(const float* __restrict__ x, const float* __restrict__ wq,
                         const float* __restrict__ wk, const float* __restrict__ wv,
                         __bf16* __restrict__ xb, __bf16* __restrict__ wqkv) {
    int i = blockIdx.x * 256 + threadIdx.x;
    float4 f;
    __bf16* dst;
    int di;
    if (i < (1 << 21)) {
        f = ((const float4*)x)[i];
        dst = xb; di = i;
    } else {
        int j = i - (1 << 21);
        const float4* s = (j < (1 << 22)) ? ((const float4*)wq + j)
                        : (j < (5 << 20)) ? ((const float4*)wk + (j - (1 << 22)))
                                          : ((const float4*)wv + (j - (5 << 20)));
        f = *s;
        dst = wqkv; di = j;
    }
    bf16x4 o;
    o[0] = (__bf16)f.x; o[1] = (__bf16)f.y; o[2] = (__bf16)f.z; o[3] = (__bf16)f.w;
    ((bf16x4*)dst)[di] = o;
}

// ---------------------------------------------------------------- m97-style NT GEMM, BK=64, XOR-swizzled LDS
constexpr int BM = 128, BN = 128, BK = 64;

__device__ inline void gld16(const __bf16* g, __bf16* l) {
    __builtin_amdgcn_global_load_lds((const __attribute__((address_space(1))) void*)g,
                                     (__attribute__((address_space(3))) void*)l, 16, 0, 0);
}

template <typename OutT>
__global__ __launch_bounds__(256) void gemm_nt(const __bf16* __restrict__ A,
                                               const __bf16* __restrict__ B,
                                               OutT* __restrict__ C,
                                               int M, int N, int K) {
    __shared__ __align__(16) __bf16 As[BM * BK];   // 16 KB
    __shared__ __align__(16) __bf16 Bs[BN * BK];   // 16 KB
    const int tid  = threadIdx.x;
    const int w    = tid >> 6, lane = tid & 63;
    const int m0   = blockIdx.y * BM, n0 = blockIdx.x * BN;
    const int wm   = (w >> 1) * 64, wn = (w & 1) * 64;
    const int lr   = lane & 15, g8 = lane >> 4;

    const int l3 = lane >> 3;
    const int lc = (lane & 7) ^ l3;
    const __bf16 *gA[4], *gB[4];
    __bf16 *lA[4], *lB[4];
#pragma unroll
    for (int c = 0; c < 4; c++) {
        int G = w * 4 + c;
        gA[c] = A + (size_t)(m0 + G * 8 + l3) * K + lc * 8;
        gB[c] = B + (size_t)(n0 + G * 8 + l3) * K + lc * 8;
        lA[c] = As + G * 512;
        lB[c] = Bs + G * 512;
    }

    f32x4 acc[4][4];
#pragma unroll
    for (int i = 0; i < 4; i++)
#pragma unroll
        for (int j = 0; j < 4; j++) acc[i][j] = (f32x4)(0.f);

    for (int k0 = 0; k0 < K; k0 += BK) {
#pragma unroll
        for (int c = 0; c < 4; c++) {
            gld16(gA[c] + k0, lA[c]);
            gld16(gB[c] + k0, lB[c]);
        }
        __syncthreads();

        const int rx = lr & 7;
#pragma unroll
        for (int kc = 0; kc < 2; kc++) {
            bf16x8 af[4], bfr[4];
#pragma unroll
            for (int i = 0; i < 4; i++)
                af[i]  = *(const bf16x8*)&As[(wm + i * 16 + lr) * BK + (((kc * 4 + g8) ^ rx) * 8)];
#pragma unroll
            for (int j = 0; j < 4; j++)
                bfr[j] = *(const bf16x8*)&Bs[(wn + j * 16 + lr) * BK + (((kc * 4 + g8) ^ rx) * 8)];
#pragma unroll
            for (int i = 0; i < 4; i++)
#pragma unroll
                for (int j = 0; j < 4; j++)
                    acc[i][j] = __builtin_amdgcn_mfma_f32_16x16x32_bf16(af[i], bfr[j], acc[i][j], 0, 0, 0);
        }
        __syncthreads();
    }

    const int cr = g8 * 4, cc = lr;
#pragma unroll
    for (int i = 0; i < 4; i++)
#pragma unroll
        for (int j = 0; j < 4; j++) {
            OutT* Cp = C + (size_t)(m0 + wm + i * 16 + cr) * N + (n0 + wn + j * 16 + cc);
#pragma unroll
            for (int r = 0; r < 4; r++) Cp[(size_t)r * N] = (OutT)acc[i][j][r];
        }
}

// ---------------------------------------------------------------- RoPE in-place on qkv bf16 [S, 6144]
__global__ void rope_qkv(__bf16* __restrict__ qkv) {
    int idx  = blockIdx.x * 256 + threadIdx.x;   // S * 40 * 64
    int d    = idx & 63;
    int rest = idx >> 6;
    int hh   = rest % (kNH + kNKV);
    int s    = rest / (kNH + kNKV);
    float inv_freq = powf(500000.0f, -(float)d * (1.0f / 64.0f));
    float sn, cs;
    sincosf((float)s * inv_freq, &sn, &cs);
    __bf16* base = qkv + (size_t)s * kQKV + ((hh < kNH) ? hh * kHD : kKOff + (hh - kNH) * kHD);
    float sc = (hh < kNH) ? 0.088388347648318447f : 1.0f;
    float a = (float)base[d], b = (float)base[d + 64];
    base[d]      = (__bf16)((a * cs - b * sn) * sc);
    base[d + 64] = (__bf16)((b * cs + a * sn) * sc);
}

// ---------------------------------------------------------------- MFMA flash attention (GQA)
// block = (kvh, 16-row q tile), grid 1024 heavy-first (R4 structure: max resident waves).
// Ks: XOR-swizzled [64k][128d] via global_load_lds (bank-uniform).
// Vt: transposed [128d][64k], conflict-free write mapping.
// Ps: bf16, XOR-swizzled 8B-granular (write 4/bank = b64 floor, read 8/bank = b128 floor).
constexpr int VTP = 72;    // Vt row stride elems

__global__ __launch_bounds__(256) void flash_attn(const __bf16* __restrict__ qkv,
                                                  __bf16* __restrict__ ob) {
    __shared__ __align__(16) __bf16 Ks[64 * 128];        // 16 KB, swizzled
    __shared__ __align__(16) __bf16 Vt[128 * VTP];       // 18 KB
    __shared__ __align__(16) __bf16 Ps[4 * 16 * 64];     // 8 KB, swizzled

    const int tid  = threadIdx.x;
    const int wave = tid >> 6, lane = tid & 63;
    const int bx   = blockIdx.x;
    const int kvh  = bx & 7;
    const int qt   = 127 - (bx >> 3);              // heavy tiles first
    const int h    = kvh * 4 + wave;
    const int r    = lane & 15, g = lane >> 4;
    const int r7   = r & 7;
    const int qglob = qt * 16 + r;

    __bf16* Pw = Ps + wave * 16 * 64;
    const __bf16* kbase = qkv + kKOff + kvh * kHD;
    const __bf16* vbase = qkv + kVOff + kvh * kHD;

    // K staging geometry (global_load_lds, slot = chunk ^ (row&15))
    int krow[4], kgc[4];
#pragma unroll
    for (int c = 0; c < 4; c++) {
        krow[c] = wave * 16 + c * 4 + (lane >> 4);
        kgc[c]  = (lane & 15) ^ (krow[c] & 15);
    }

    bf16x8 qfrag[4];
    const __bf16* qrow = qkv + (size_t)(qt * 16 + r) * kQKV + h * kHD + g * 8;
#pragma unroll
    for (int c = 0; c < 4; c++) qfrag[c] = *(const bf16x8*)(qrow + c * 32);

    f32x4 o[8];
#pragma unroll
    for (int dt = 0; dt < 8; dt++) o[dt] = (f32x4)(0.f);
    float mrow = -3.0e38f, lrow = 0.f;

    const int nkt = qt / 4 + 1;
    for (int kt = 0; kt < nkt; ++kt) {
        // ---- stage K via async global->LDS (swizzled)
#pragma unroll
        for (int c = 0; c < 4; c++)
            gld16(kbase + (size_t)(kt * 64 + krow[c]) * kQKV + kgc[c] * 8,
                  Ks + (wave * 4 + c) * 512);
        // ---- stage V transposed: conflict-free mapping (2-way max)
#pragma unroll
        for (int i = 0; i < 2; i++) {
            int task = i * 256 + tid;
            int p = task & 31, c = task >> 5;   // p: key pair, c: 8-d chunk
            const __bf16* v0 = vbase + (size_t)(kt * 64 + 2 * p) * kQKV + c * 8;
            u16x8 a = __builtin_bit_cast(u16x8, *(const bf16x8*)v0);
            u16x8 b = __builtin_bit_cast(u16x8, *(const bf16x8*)(v0 + kQKV));
#pragma unroll
            for (int j = 0; j < 8; j++) {
                unsigned int pk = (unsigned int)a[j] | ((unsigned int)b[j] << 16);
                *(unsigned int*)(Vt + (c * 8 + j) * VTP + 2 * p) = pk;
            }
        }
        __syncthreads();

        // ---- S^T = K·Q^T  (Ks read honors the XOR swizzle)
        f32x4 st[4];
#pragma unroll
        for (int t = 0; t < 4; t++) st[t] = (f32x4)(0.f);
#pragma unroll
        for (int c = 0; c < 4; c++) {
#pragma unroll
            for (int t = 0; t < 4; t++) {
                bf16x8 kf = *(const bf16x8*)&Ks[(t * 16 + r) * 128 + (((c * 4 + g) ^ r) * 8)];
                st[t] = __builtin_amdgcn_mfma_f32_16x16x32_bf16(kf, qfrag[c], st[t], 0, 0, 0);
            }
        }

        // ---- causal mask: only the diagonal tile can violate
        if (kt == nkt - 1) {
#pragma unroll
            for (int t = 0; t < 4; t++)
#pragma unroll
                for (int reg = 0; reg < 4; reg++) {
                    int key = kt * 64 + t * 16 + g * 4 + reg;
                    if (key > qglob) st[t][reg] = -3.0e38f;
                }
        }

        // ---- online softmax (per q = r)
        float mloc = -3.0e38f;
#pragma unroll
        for (int t = 0; t < 4; t++)
#pragma unroll
            for (int reg = 0; reg < 4; reg++) mloc = fmaxf(mloc, st[t][reg]);
        mloc = fmaxf(mloc, __shfl_xor(mloc, 16));
        mloc = fmaxf(mloc, __shfl_xor(mloc, 32));
        float mnew  = fmaxf(mrow, mloc);
        float alpha = __expf(mrow - mnew);
        mrow = mnew;
        float lsum = 0.f;
#pragma unroll
        for (int t = 0; t < 4; t++)
#pragma unroll
            for (int reg = 0; reg < 4; reg++) {
                float pv = __expf(st[t][reg] - mnew);
                st[t][reg] = pv;
                lsum += pv;
            }
        lsum += __shfl_xor(lsum, 16);
        lsum += __shfl_xor(lsum, 32);
        lrow = lrow * alpha + lsum;

        float ar[4];
#pragma unroll
        for (int reg = 0; reg < 4; reg++) ar[reg] = __shfl(alpha, g * 4 + reg);
#pragma unroll
        for (int dt = 0; dt < 8; dt++)
#pragma unroll
            for (int reg = 0; reg < 4; reg++) o[dt][reg] *= ar[reg];

        // ---- P (bf16): C-layout -> LDS -> A-layout, XOR-swizzled 8B slots
        // write: piece p8 = t*4+g (8B) stored at chunk ((p8>>1) ^ r7), half p8&1
#pragma unroll
        for (int t = 0; t < 4; t++) {
            bf16x4 pb;
#pragma unroll
            for (int j = 0; j < 4; j++) pb[j] = (__bf16)st[t][j];
            int p8 = t * 4 + g;
            *(bf16x4*)&Pw[r * 64 + (((p8 >> 1) ^ r7) * 8) + ((p8 & 1) * 4)] = pb;
        }
        __asm__ volatile("s_waitcnt lgkmcnt(0)" ::: "memory");

#pragma unroll
        for (int kc = 0; kc < 2; kc++) {
            bf16x8 pf = *(const bf16x8*)&Pw[r * 64 + (((kc * 4 + g) ^ r7) * 8)];
#pragma unroll
            for (int dt = 0; dt < 8; dt++) {
                bf16x8 vf = *(const bf16x8*)&Vt[(dt * 16 + r) * VTP + kc * 32 + g * 8];
                o[dt] = __builtin_amdgcn_mfma_f32_16x16x32_bf16(pf, vf, o[dt], 0, 0, 0);
            }
        }
        __syncthreads();
    }

    // ---- epilogue
    float linv = 1.f / lrow;
    float lr4[4];
#pragma unroll
    for (int reg = 0; reg < 4; reg++) lr4[reg] = __shfl(linv, g * 4 + reg);
#pragma unroll
    for (int dt = 0; dt < 8; dt++)
#pragma unroll
        for (int reg = 0; reg < 4; reg++) {
            int qq = g * 4 + reg, dd = dt * 16 + r;
            ob[(size_t)(qt * 16 + qq) * kH + h * kHD + dd] = (__bf16)(o[dt][reg] * lr4[reg]);
        }
}

// ---------------------------------------------------------------- launch
extern "C" void kernel_launch(void* const* d_in, const int* in_sizes, int n_in,
                              void* d_out, int out_size, void* d_ws, size_t ws_size,
                              hipStream_t stream) {
    const float* x  = (const float*)d_in[0];
    const float* wq = (const float*)d_in[1];
    const float* wk = (const float*)d_in[2];
    const float* wv = (const float*)d_in[3];
    const float* wo = (const float*)d_in[4];
    float* out = (float*)d_out;

    char* p = (char*)d_ws;
    auto alloc = [&](size_t bytes) {
        char* r = p;
        p += (bytes + 255) & ~(size_t)255;
        return r;
    };
    __bf16* xb    = (__bf16*)alloc((size_t)kS * kH * 2);        // 16 MB; later attn out
    __bf16* wqkvb = (__bf16*)alloc((size_t)kQKV * kH * 2);      // 48 MB; later wo bf16
    __bf16* qkv   = (__bf16*)alloc((size_t)kS * kQKV * 2);      // 24 MB
    __bf16* ao    = xb;
    __bf16* wob   = wqkvb;

    cast_all<<<dim3(1 << 15), 256, 0, stream>>>(x, wq, wk, wv, xb, wqkvb);

    gemm_nt<__bf16><<<dim3(kQKV / BN, kS / BM), 256, 0, stream>>>(xb, wqkvb, qkv, kS, kQKV, kH);

    rope_qkv<<<dim3(kS * (kNH + kNKV) * 64 / 256), 256, 0, stream>>>(qkv);

    cast_bf16<<<dim3((kH * kH / 4) / 256), 256, 0, stream>>>(wo, wob, kH * kH / 4);

    flash_attn<<<dim3(kNKV * (kS / 16)), 256, 0, stream>>>(qkv, ao);

    gemm_nt<float><<<dim3(kH / BN, kS / BM), 256, 0, stream>>>(ao, wob, out, kS, kH, kH);
}